// Round 4
// baseline (617.161 us; speedup 1.0000x reference)
//
#include <hip/hip_runtime.h>
#include <hip/hip_bf16.h>

#define NUM_CLASSES 21
#define CHANNELS 256
#define CPAD 257            // bank = (l*257 + c) % 32 = (l + c) % 32 -> 21 distinct banks per instr
#define B_SZ 16
#define HF 128
#define WF 128
#define HL 512
#define WL 512
#define PIX_PER_BLOCK 512   // 2 pixels per thread, 256 threads
#define TILES_PER_B (HF * WF / PIX_PER_BLOCK)  // 32

// Accumulate per-class channel sums and pixel counts.
// Grid: 16 * 32 = 512 blocks (2/CU, 8 waves/CU), 256 threads.
__global__ __launch_bounds__(256) void protos_accum_kernel(
    const float* __restrict__ feats,   // [16][256][128][128]
    const int*   __restrict__ labels,  // [16][512][512]
    float* __restrict__ sums,          // [21][256] (d_ws)
    int*   __restrict__ counts)        // [21]      (d_ws)
{
    __shared__ float acc[NUM_CLASSES][CPAD];
    __shared__ int   cnt[NUM_CLASSES];

    const int t = threadIdx.x;

    // zero LDS accumulators
    for (int i = t; i < NUM_CLASSES * CPAD; i += 256) ((float*)acc)[i] = 0.0f;
    if (t < NUM_CLASSES) cnt[t] = 0;
    __syncthreads();

    const int b    = blockIdx.x >> 5;          // / TILES_PER_B
    const int tile = blockIdx.x & 31;
    const int base = tile * PIX_PER_BLOCK;     // contiguous pixel range in the 128x128 plane

    const int p0 = base + 2 * t;
    const int p1 = p0 + 1;
    const int h0 = p0 >> 7, w0 = p0 & 127;
    const int h1 = p1 >> 7, w1 = p1 & 127;

    // nearest resize: src = floor(dst * 512/128) = dst * 4
    const int l0 = labels[(size_t)b * (HL * WL) + (size_t)(h0 * 4) * WL + w0 * 4];
    const int l1 = labels[(size_t)b * (HL * WL) + (size_t)(h1 * 4) * WL + w1 * 4];

    atomicAdd(&cnt[l0], 1);   // int atomic: native ds_add_u32
    atomicAdd(&cnt[l1], 1);

    const float* fbase = feats + (size_t)b * CHANNELS * (HF * WF) + base + 2 * t;

    // native ds_add_f32 (fire-and-forget, no CAS loop); 8 loads in flight per wave
    #pragma unroll 8
    for (int c = 0; c < CHANNELS; ++c) {
        const float2 v = *(const float2*)(fbase + (size_t)c * (HF * WF));
        unsafeAtomicAdd(&acc[l0][c], v.x);
        unsafeAtomicAdd(&acc[l1][c], v.y);
    }
    __syncthreads();

    // flush block-private accumulators to global (native global_atomic_add_f32)
    for (int i = t; i < NUM_CLASSES * CHANNELS; i += 256) {
        const int k = i >> 8;       // / 256
        const int c = i & 255;
        unsafeAtomicAdd(&sums[i], acc[k][c]);
    }
    if (t < NUM_CLASSES) atomicAdd(&counts[t], cnt[t]);  // int: native
}

// Grid: 21 blocks x 256 threads. out = [21*256 protos][21 counts]
__global__ __launch_bounds__(256) void protos_finalize_kernel(
    const float* __restrict__ sums,
    const int*   __restrict__ counts,
    float* __restrict__ out)
{
    const int k = blockIdx.x;
    const int c = threadIdx.x;
    const float cn = (float)counts[k];
    const float p = (cn > 0.0f) ? (sums[k * CHANNELS + c] / fmaxf(cn, 1.0f)) : 0.0f;
    out[k * CHANNELS + c] = p;
    if (c == 0) out[NUM_CLASSES * CHANNELS + k] = cn;
}

extern "C" void kernel_launch(void* const* d_in, const int* in_sizes, int n_in,
                              void* d_out, int out_size, void* d_ws, size_t ws_size,
                              hipStream_t stream) {
    const float* feats  = (const float*)d_in[0];
    const int*   labels = (const int*)d_in[1];
    float* sums   = (float*)d_ws;                          // [21*256]
    int*   counts = (int*)(sums + NUM_CLASSES * CHANNELS); // [21]
    float* out    = (float*)d_out;

    // zero the workspace accumulators (harness poisons d_ws before every call)
    hipMemsetAsync(d_ws, 0,
                   (NUM_CLASSES * CHANNELS) * sizeof(float) + NUM_CLASSES * sizeof(int),
                   stream);

    dim3 grid(B_SZ * TILES_PER_B);   // 512
    dim3 block(256);
    protos_accum_kernel<<<grid, block, 0, stream>>>(feats, labels, sums, counts);

    protos_finalize_kernel<<<dim3(NUM_CLASSES), dim3(CHANNELS), 0, stream>>>(sums, counts, out);
}

// Round 5
// 412.087 us; speedup vs baseline: 1.4976x; 1.4976x over previous
//
#include <hip/hip_runtime.h>
#include <hip/hip_bf16.h>

#define NUM_CLASSES 21
#define CHANNELS 256
#define B_SZ 16
#define HF 128
#define WF 128
#define HL 512
#define WL 512
#define PIX_PER_BLOCK 512
#define TILES_PER_B (HF * WF / PIX_PER_BLOCK)   // 32
#define PCHUNK 64
#define NCHUNK (PIX_PER_BLOCK / PCHUNK)          // 8
#define FPAD 65   // row stride (floats): read bank = (t+p)%32 -> 2-way (free, m136)

// Thread t owns channel t. No per-element atomics anywhere.
// Grid: 16*32 = 512 blocks (2/CU via 68.8KB LDS), 256 threads.
__global__ __launch_bounds__(256) void protos_accum_kernel(
    const float* __restrict__ feats,   // [16][256][128][128]
    const int*   __restrict__ labels,  // [16][512][512]
    float* __restrict__ sums,          // [21][256] (d_ws)
    int*   __restrict__ counts)        // [21]      (d_ws)
{
    __shared__ float fbuf[CHANNELS * FPAD];   // 66,560 B, [c][p] padded
    __shared__ int   lbl[PIX_PER_BLOCK];
    __shared__ int   cnt[NUM_CLASSES];

    const int t    = threadIdx.x;
    const int lane = t & 63;
    const int b    = blockIdx.x >> 5;
    const int tile = blockIdx.x & 31;
    const int base = tile * PIX_PER_BLOCK;

    if (t < NUM_CLASSES) cnt[t] = 0;

    // tile labels: 2 per thread (nearest resize: src = dst*4)
    const int p0 = base + 2 * t;
    const int h0 = p0 >> 7,       w0 = p0 & 127;
    const int h1 = (p0 + 1) >> 7, w1 = (p0 + 1) & 127;
    const int l0 = labels[(size_t)b * (HL * WL) + (size_t)(h0 * 4) * WL + w0 * 4];
    const int l1 = labels[(size_t)b * (HL * WL) + (size_t)(h1 * 4) * WL + w1 * 4];
    lbl[2 * t]     = l0;
    lbl[2 * t + 1] = l1;
    __syncthreads();
    atomicAdd(&cnt[l0], 1);   // once per pixel per block: negligible
    atomicAdd(&cnt[l1], 1);

    float acc[NUM_CLASSES];
    #pragma unroll
    for (int k = 0; k < NUM_CLASSES; ++k) acc[k] = 0.0f;

    const float* fb = feats + (size_t)b * CHANNELS * (HF * WF);

    for (int chk = 0; chk < NCHUNK; ++chk) {
        const int pbase = base + chk * PCHUNK;

        // issue all 16 global float4 loads first (overlaps previous consume)
        float4 v[16];
        #pragma unroll
        for (int i = 0; i < 16; ++i) {
            const int flat = i * 256 + t;          // float4 slot in [256ch][16 q]
            const int c = flat >> 4;
            const int q = flat & 15;
            v[i] = *(const float4*)(fb + (size_t)c * (HF * WF) + pbase + q * 4);
        }
        __syncthreads();   // previous chunk fully consumed before overwrite

        // element-wise stores (stride 65 is not 16B-aligned; compiler pairs to ds_write2)
        #pragma unroll
        for (int i = 0; i < 16; ++i) {
            const int flat = i * 256 + t;
            const int c = flat >> 4;
            const int q = flat & 15;
            float* d = &fbuf[c * FPAD + q * 4];
            d[0] = v[i].x; d[1] = v[i].y; d[2] = v[i].z; d[3] = v[i].w;
        }
        __syncthreads();

        // lane i of every wave holds label of pixel chk*64+i
        const int mylbl = lbl[chk * PCHUNK + lane];
        const float* frow = &fbuf[t * FPAD];

        #pragma unroll 8
        for (int p = 0; p < PCHUNK; ++p) {
            const float vv = frow[p];                              // 2-way banked, free
            const int lb = __builtin_amdgcn_readlane(mylbl, p);    // SGPR label -> scalar branches
            switch (lb) {
                case 0:  acc[0]  += vv; break;
                case 1:  acc[1]  += vv; break;
                case 2:  acc[2]  += vv; break;
                case 3:  acc[3]  += vv; break;
                case 4:  acc[4]  += vv; break;
                case 5:  acc[5]  += vv; break;
                case 6:  acc[6]  += vv; break;
                case 7:  acc[7]  += vv; break;
                case 8:  acc[8]  += vv; break;
                case 9:  acc[9]  += vv; break;
                case 10: acc[10] += vv; break;
                case 11: acc[11] += vv; break;
                case 12: acc[12] += vv; break;
                case 13: acc[13] += vv; break;
                case 14: acc[14] += vv; break;
                case 15: acc[15] += vv; break;
                case 16: acc[16] += vv; break;
                case 17: acc[17] += vv; break;
                case 18: acc[18] += vv; break;
                case 19: acc[19] += vv; break;
                case 20: acc[20] += vv; break;
                default: break;
            }
        }
        // next iteration's pre-store barrier protects fbuf
    }

    // flush: 21 coalesced global atomics per thread (contiguous across t for each k)
    #pragma unroll
    for (int k = 0; k < NUM_CLASSES; ++k)
        unsafeAtomicAdd(&sums[k * CHANNELS + t], acc[k]);
    if (t < NUM_CLASSES) atomicAdd(&counts[t], cnt[t]);
}

// Grid: 21 blocks x 256 threads. out = [21*256 protos][21 counts]
__global__ __launch_bounds__(256) void protos_finalize_kernel(
    const float* __restrict__ sums,
    const int*   __restrict__ counts,
    float* __restrict__ out)
{
    const int k = blockIdx.x;
    const int c = threadIdx.x;
    const float cn = (float)counts[k];
    const float p = (cn > 0.0f) ? (sums[k * CHANNELS + c] / fmaxf(cn, 1.0f)) : 0.0f;
    out[k * CHANNELS + c] = p;
    if (c == 0) out[NUM_CLASSES * CHANNELS + k] = cn;
}

extern "C" void kernel_launch(void* const* d_in, const int* in_sizes, int n_in,
                              void* d_out, int out_size, void* d_ws, size_t ws_size,
                              hipStream_t stream) {
    const float* feats  = (const float*)d_in[0];
    const int*   labels = (const int*)d_in[1];
    float* sums   = (float*)d_ws;                          // [21*256]
    int*   counts = (int*)(sums + NUM_CLASSES * CHANNELS); // [21]
    float* out    = (float*)d_out;

    hipMemsetAsync(d_ws, 0,
                   (NUM_CLASSES * CHANNELS) * sizeof(float) + NUM_CLASSES * sizeof(int),
                   stream);

    dim3 grid(B_SZ * TILES_PER_B);   // 512
    dim3 block(256);
    protos_accum_kernel<<<grid, block, 0, stream>>>(feats, labels, sums, counts);

    protos_finalize_kernel<<<dim3(NUM_CLASSES), dim3(CHANNELS), 0, stream>>>(sums, counts, out);
}